// Round 2
// baseline (199.411 us; speedup 1.0000x reference)
//
#include <hip/hip_runtime.h>
#include <hip/hip_bf16.h>

#define NT 10      // spline knots
#define NC 256     // channels
#define EPS 1e-5f
#define HW4 784    // (56*56)/4 float4s per (b,c) plane

// ---------------------------------------------------------------------------
// Kernel 1: one thread per channel. Natural cubic spline coefficients via
// Thomas algorithm on the (NT-2)x(NT-2) tridiagonal system, evaluated at t.
// Writes scale[c] to ws[c], shift[c] to ws[NC + c].
// ---------------------------------------------------------------------------
__device__ float spline_eval_channel(const float* __restrict__ param, // [NT, NC]
                                     const float* __restrict__ times,
                                     float t, int c) {
    float y[NT];
#pragma unroll
    for (int i = 0; i < NT; ++i) y[i] = param[i * NC + c];

    float h[NT - 1], slopes[NT - 1];
#pragma unroll
    for (int i = 0; i < NT - 1; ++i) {
        h[i] = times[i + 1] - times[i];
        slopes[i] = (y[i + 1] - y[i]) / h[i];
    }

    // Tridiagonal system for interior second derivatives m[1..NT-2].
    float rhs[NT - 2], diag[NT - 2], sup[NT - 3];
#pragma unroll
    for (int i = 0; i < NT - 2; ++i) {
        rhs[i]  = 6.0f * (slopes[i + 1] - slopes[i]);
        diag[i] = 2.0f * (h[i] + h[i + 1]);
    }
#pragma unroll
    for (int i = 0; i < NT - 3; ++i) sup[i] = h[i + 1];  // super == sub

    // Thomas forward elimination
#pragma unroll
    for (int i = 1; i < NT - 2; ++i) {
        float w = sup[i - 1] / diag[i - 1];
        diag[i] -= w * sup[i - 1];
        rhs[i]  -= w * rhs[i - 1];
    }
    // Back substitution
    float m[NT];
    m[0] = 0.0f;
    m[NT - 1] = 0.0f;
    m[NT - 2] = rhs[NT - 3] / diag[NT - 3];
#pragma unroll
    for (int i = NT - 4; i >= 0; --i)
        m[i + 1] = (rhs[i] - sup[i] * m[i + 2]) / diag[i];

    // Interval: idx = clip(searchsorted(times, t, 'right') - 1, 0, NT-2)
    int idx = 0;
#pragma unroll
    for (int i = 1; i <= NT - 2; ++i)
        if (times[i] <= t) idx = i;

    float u  = t - times[idx];
    float b  = slopes[idx] - h[idx] * (2.0f * m[idx] + m[idx + 1]) * (1.0f / 6.0f);
    float cc = m[idx] * 0.5f;
    float d  = (m[idx + 1] - m[idx]) / (6.0f * h[idx]);
    return y[idx] + u * (b + u * (cc + u * d));
}

__global__ void spline_coeffs_kernel(const float* __restrict__ means,
                                     const float* __restrict__ vars_,
                                     const float* __restrict__ bnw,
                                     const float* __restrict__ bnb,
                                     const float* __restrict__ times_g,
                                     const float* __restrict__ t_g,
                                     float* __restrict__ ws) {
    __shared__ float times[NT];
    if (threadIdx.x < NT) times[threadIdx.x] = times_g[threadIdx.x];
    __syncthreads();
    const float t = t_g[0];
    const int c = threadIdx.x;  // 256 threads == 256 channels

    float mean   = spline_eval_channel(means, times, t, c);
    float var    = spline_eval_channel(vars_, times, t, c);
    float weight = spline_eval_channel(bnw,   times, t, c);
    float bias   = spline_eval_channel(bnb,   times, t, c);

    float inv = 1.0f / sqrtf(var + EPS);
    float s   = weight * inv;
    ws[c]        = s;                 // scale
    ws[NC + c]   = bias - mean * s;   // shift
}

// ---------------------------------------------------------------------------
// Kernel 2: grid-stride float4 elementwise  out = x*scale[c] + shift[c]
// ---------------------------------------------------------------------------
__global__ void apply_kernel(const float4* __restrict__ x,
                             const float* __restrict__ ws,
                             float4* __restrict__ out, int n4) {
    const float* __restrict__ scale = ws;
    const float* __restrict__ shift = ws + NC;
    int stride = gridDim.x * blockDim.x;
    for (int i = blockIdx.x * blockDim.x + threadIdx.x; i < n4; i += stride) {
        int c = (i / HW4) & (NC - 1);
        float s  = scale[c];
        float sh = shift[c];
        float4 v = x[i];
        v.x = fmaf(v.x, s, sh);
        v.y = fmaf(v.y, s, sh);
        v.z = fmaf(v.z, s, sh);
        v.w = fmaf(v.w, s, sh);
        out[i] = v;
    }
}

extern "C" void kernel_launch(void* const* d_in, const int* in_sizes, int n_in,
                              void* d_out, int out_size, void* d_ws, size_t ws_size,
                              hipStream_t stream) {
    const float* x     = (const float*)d_in[0];
    const float* means = (const float*)d_in[1];
    const float* vars_ = (const float*)d_in[2];
    const float* bnw   = (const float*)d_in[3];
    const float* bnb   = (const float*)d_in[4];
    const float* times = (const float*)d_in[5];
    const float* t     = (const float*)d_in[6];
    float* out = (float*)d_out;
    float* ws  = (float*)d_ws;   // [2*NC] floats: scale then shift

    spline_coeffs_kernel<<<1, NC, 0, stream>>>(means, vars_, bnw, bnb, times, t, ws);

    int n4 = out_size / 4;  // HW=3136 divisible by 4, so exact
    int threads = 256;
    int blocks = (n4 + threads - 1) / threads;
    if (blocks > 2048) blocks = 2048;
    apply_kernel<<<blocks, threads, 0, stream>>>((const float4*)x, ws, (float4*)out, n4);
}

// Round 4
// 193.126 us; speedup vs baseline: 1.0325x; 1.0325x over previous
//
#include <hip/hip_runtime.h>
#include <hip/hip_bf16.h>

#define NT 10      // spline knots
#define NC 256     // channels
#define EPS 1e-5f
#define HW4 784    // (56*56)/4 float4s per (b,c) plane

// ---------------------------------------------------------------------------
// Kernel 1: one thread per channel. Natural cubic spline via Thomas algorithm.
// ALL arrays statically indexed after full unroll; interval selection is an
// unrolled conditional-move chain => no scratch (rule #20).
// ---------------------------------------------------------------------------
__device__ __forceinline__ float spline_eval_channel(
        const float* __restrict__ param,   // [NT, NC]
        const float* __restrict__ times,   // LDS, [NT]
        float t, int c) {
    float y[NT];
#pragma unroll
    for (int i = 0; i < NT; ++i) y[i] = param[i * NC + c];

    float h[NT - 1], slopes[NT - 1];
#pragma unroll
    for (int i = 0; i < NT - 1; ++i) {
        h[i] = times[i + 1] - times[i];
        slopes[i] = (y[i + 1] - y[i]) / h[i];
    }

    float rhs[NT - 2], diag[NT - 2], sup[NT - 3];
#pragma unroll
    for (int i = 0; i < NT - 2; ++i) {
        rhs[i]  = 6.0f * (slopes[i + 1] - slopes[i]);
        diag[i] = 2.0f * (h[i] + h[i + 1]);
    }
#pragma unroll
    for (int i = 0; i < NT - 3; ++i) sup[i] = h[i + 1];

    // Thomas forward elimination (static indices after unroll)
#pragma unroll
    for (int i = 1; i < NT - 2; ++i) {
        float w = sup[i - 1] / diag[i - 1];
        diag[i] -= w * sup[i - 1];
        rhs[i]  -= w * rhs[i - 1];
    }
    float m[NT];
    m[0] = 0.0f;
    m[NT - 1] = 0.0f;
    m[NT - 2] = rhs[NT - 3] / diag[NT - 3];
#pragma unroll
    for (int i = NT - 4; i >= 0; --i)
        m[i + 1] = (rhs[i] - sup[i] * m[i + 2]) / diag[i];

    // Per-interval cubic coefficients (all static)
    float bco[NT - 1], cco[NT - 1], dco[NT - 1];
#pragma unroll
    for (int i = 0; i < NT - 1; ++i) {
        bco[i] = slopes[i] - h[i] * (2.0f * m[i] + m[i + 1]) * (1.0f / 6.0f);
        cco[i] = m[i] * 0.5f;
        dco[i] = (m[i + 1] - m[i]) / (6.0f * h[i]);
    }

    // idx = clip(searchsorted(times,t,'right')-1, 0, NT-2) as a cndmask chain
    float A = y[0], Bf = bco[0], Cf = cco[0], Df = dco[0], u = t - times[0];
#pragma unroll
    for (int i = 1; i <= NT - 2; ++i) {
        bool sel = (times[i] <= t);
        if (sel) { A = y[i]; Bf = bco[i]; Cf = cco[i]; Df = dco[i]; u = t - times[i]; }
    }
    return A + u * (Bf + u * (Cf + u * Df));
}

__global__ void spline_coeffs_kernel(const float* __restrict__ means,
                                     const float* __restrict__ vars_,
                                     const float* __restrict__ bnw,
                                     const float* __restrict__ bnb,
                                     const float* __restrict__ times_g,
                                     const float* __restrict__ t_g,
                                     float* __restrict__ ws) {
    __shared__ float times[NT];
    if (threadIdx.x < NT) times[threadIdx.x] = times_g[threadIdx.x];
    __syncthreads();
    const float t = t_g[0];
    const int c = threadIdx.x;  // 256 threads == 256 channels

    float mean   = spline_eval_channel(means, times, t, c);
    float var    = spline_eval_channel(vars_, times, t, c);
    float weight = spline_eval_channel(bnw,   times, t, c);
    float bias   = spline_eval_channel(bnb,   times, t, c);

    float inv = 1.0f / sqrtf(var + EPS);
    float s   = weight * inv;
    ws[c]      = s;               // scale
    ws[NC + c] = bias - mean * s; // shift
}

// ---------------------------------------------------------------------------
// Kernel 2: one float4 per thread (exact grid, no loop).
//   out[i] = x[i] * scale[c] + shift[c],  c = (i / HW4) & 255
// ---------------------------------------------------------------------------
__global__ void apply_kernel(const float4* __restrict__ x,
                             const float* __restrict__ ws,
                             float4* __restrict__ out, int n4) {
    int i = blockIdx.x * blockDim.x + threadIdx.x;
    if (i >= n4) return;
    int c = (i / HW4) & (NC - 1);
    float s  = ws[c];
    float sh = ws[NC + c];
    float4 v = x[i];
    v.x = fmaf(v.x, s, sh);
    v.y = fmaf(v.y, s, sh);
    v.z = fmaf(v.z, s, sh);
    v.w = fmaf(v.w, s, sh);
    out[i] = v;
}

extern "C" void kernel_launch(void* const* d_in, const int* in_sizes, int n_in,
                              void* d_out, int out_size, void* d_ws, size_t ws_size,
                              hipStream_t stream) {
    const float* x     = (const float*)d_in[0];
    const float* means = (const float*)d_in[1];
    const float* vars_ = (const float*)d_in[2];
    const float* bnw   = (const float*)d_in[3];
    const float* bnb   = (const float*)d_in[4];
    const float* times = (const float*)d_in[5];
    const float* t     = (const float*)d_in[6];
    float* out = (float*)d_out;
    float* ws  = (float*)d_ws;   // [2*NC] floats: scale then shift

    spline_coeffs_kernel<<<1, NC, 0, stream>>>(means, vars_, bnw, bnb, times, t, ws);

    int n4 = out_size / 4;                  // 6,422,528
    int threads = 256;
    int blocks = (n4 + threads - 1) / threads;  // 25088, exact
    apply_kernel<<<blocks, threads, 0, stream>>>((const float4*)x, ws, (float4*)out, n4);
}